// Round 5
// baseline (1399.910 us; speedup 1.0000x reference)
//
#include <hip/hip_runtime.h>
#include <hip/hip_bf16.h>
#include <stdint.h>

// Problem constants
#define B_  32
#define S_  2048
#define H_  1024
#define K_  2048   // 2H, GEMM reduction dim
#define M_  65536  // B*S

typedef __bf16 bf16x8 __attribute__((ext_vector_type(8)));
typedef float  f32x4  __attribute__((ext_vector_type(4)));

__device__ __forceinline__ unsigned short f2bf(float x) {
    unsigned u = __builtin_bit_cast(unsigned, x);
    u += 0x7fffu + ((u >> 16) & 1u);
    return (unsigned short)(u >> 16);
}

__device__ __forceinline__ unsigned pk_bf16(float x, float y) {
#if __has_builtin(__builtin_amdgcn_cvt_pk_bf16_f32)
    auto r = __builtin_amdgcn_cvt_pk_bf16_f32(x, y);
    static_assert(sizeof(r) == 4, "cvt_pk_bf16 size");
    return __builtin_bit_cast(unsigned, r);
#else
    return ((unsigned)f2bf(x)) | ((unsigned)f2bf(y) << 16);
#endif
}

__device__ __forceinline__ float tanh_fast(float x) {
    float e = __expf(2.0f * x);
    return 1.0f - 2.0f / (e + 1.0f);
}

// ---------------------------------------------------------------- fp32 -> bf16 (W_enc only now)
__global__ __launch_bounds__(256) void cast8_k(const float* __restrict__ in,
                                               unsigned short* __restrict__ o, long n8) {
    const long stride = (long)gridDim.x * 256;
    for (long i = (long)blockIdx.x * 256 + threadIdx.x; i < n8; i += stride) {
        const float4* p = (const float4*)(in + i * 8);
        float4 a = p[0], b = p[1];
        uint4 pk;
        pk.x = pk_bf16(a.x, a.y);
        pk.y = pk_bf16(a.z, a.w);
        pk.z = pk_bf16(b.x, b.y);
        pk.w = pk_bf16(b.z, b.w);
        *(uint4*)(o + i * 8) = pk;
    }
}

// ---------------------------------------------------------------- dec = dec_state @ W_dec^T
__global__ __launch_bounds__(256) void dec_k(const float* __restrict__ ds,
                                             const float* __restrict__ Wd,
                                             float* __restrict__ decv) {
    const int b = blockIdx.y;
    const int w = threadIdx.x >> 6, lane = threadIdx.x & 63;
    const int h = blockIdx.x * 4 + w;
    const float* wr = Wd + (long)h * H_;
    const float* dr = ds + (long)b * H_;
    float acc = 0.f;
#pragma unroll
    for (int i = 0; i < 4; i++) {
        int idx = lane * 4 + i * 256;
        float4 a = *(const float4*)(wr + idx);
        float4 d = *(const float4*)(dr + idx);
        acc += a.x * d.x + a.y * d.y + a.z * d.z + a.w * d.w;
    }
    for (int m2 = 1; m2 < 64; m2 <<= 1) acc += __shfl_xor(acc, m2, 64);
    if (lane == 0) decv[(long)b * H_ + h] = acc;
}

// ================================================================ gemm_v5:
// 128x128 tile, 4 waves (2M x 2N, 64x64/wave), 24 KiB LDS -> 3 blocks/CU
// (barrier-decoupled, m97/m114 overlap mechanism). A: fp32 from global,
// reg-staged + cvt_pk -> ds_write into a 3-slot fragment-order kh ring
// (fuses the enc cast into the GEMM). B: bf16 W_enc frags loaded directly
// from L2 into double-buffered regs (no LDS, no DMA). All cross-phase
// ordering via register deps (compiler auto vmcnt; loads stay in flight
// across barriers) + one lgkmcnt(0)+barrier per phase (publishes ds_write).
//
// LDS slot (8 KiB) = 512 granules of 16 B; granule u = (row>>4)*64 +
// (col8)*16 + (row&15) holds A[row][col8*8..+7] bf16 — exact MFMA A-frag
// order, so ds_read_b128 is lane-linear (0 conflicts, measured r2-r4).
//
// Phase p (= kh):
//   ds_write A(kh+1) -> slot (srd+1)%3   [from sa regs loaded at p-1]
//   issue A-fp32 loads(kh+2) -> sa       [4x float4, coalesced]
//   issue B-frag loads(kh+1) -> BQnxt    [4x 16B/lane, L2]
//   s_waitcnt lgkmcnt(0); s_barrier      [publish; VMEM stays in flight]
//   ds_read 4 A-frags (slot srd); 16 MFMA with BQcur
// Ring safety: slot written at p was read at p-2; barriers p-1,p separate.
__global__ __launch_bounds__(256, 3) void gemm_fast(const float* __restrict__ A,
                                                    const unsigned short* __restrict__ Bw,
                                                    const float* __restrict__ decv,
                                                    const float* __restrict__ Weng,
                                                    float* __restrict__ pe) {
    __shared__ __align__(1024) unsigned short LDS[12288];  // 3 slots x 4096 ushort (24 KiB)

    // Bijective XCD swizzle: 8 nb-blocks of an mb on one XCD (A L2 reuse).
    const int L = blockIdx.x;          // 4096 = 64 * 8 * 8
    const int xcd = L & 7;
    const int sl = L >> 3;             // 0..511
    const int nb = sl & 7;             // 8 n-blocks (N=1024, BN=128)
    const int mb = (sl >> 3) * 8 + xcd; // 0..511 (M=65536, BM=128)

    const int t = threadIdx.x;
    const int lane = t & 63;
    const int w = t >> 6;              // 4 waves: 2M x 2N
    const int WR = w >> 1, WC = w & 1;
    const int r = lane & 15, g = (lane >> 4) & 3;

    f32x4 acc[4][4];
#pragma unroll
    for (int mi = 0; mi < 4; mi++)
#pragma unroll
        for (int ni = 0; ni < 4; ni++)
#pragma unroll
            for (int k = 0; k < 4; k++) acc[mi][ni][k] = 0.f;

    // A staging map: thread t handles row R = t>>1, fp32 cols ch*16..+15.
    const int R = t >> 1, ch = t & 1;
    const float* aCur = A + (long)(mb * 128 + R) * K_ + ch * 16;
    // write granules: u = (R>>4)*64 + (ch*2)*16 + (R&15), and u+16
    const int wrE = (((R >> 4) << 6) + ((ch * 2) << 4) + (R & 15)) * 8;  // ushort index
    // read granules: u = (WR*4+mi)*64 + g*16 + r  -> ushort index +512/mi
    const int rdE = (((WR * 4) << 6) + (g << 4) + r) * 8;

    // B source: per-lane row (h) = nb*128 + WC*64 + ni*16 + r, cols kh*32+g*8
    const unsigned short* bCur = Bw + (long)(nb * 128 + WC * 64 + r) * K_ + g * 8;

    float4 sa0, sa1, sa2, sa3;
    bf16x8 bqA0, bqA1, bqA2, bqA3, bqB0, bqB1, bqB2, bqB3;
    int srd = 0;

#define STAGEWR(SLOT) do { \
    uint4 w0, w1; \
    w0.x = pk_bf16(sa0.x, sa0.y); w0.y = pk_bf16(sa0.z, sa0.w); \
    w0.z = pk_bf16(sa1.x, sa1.y); w0.w = pk_bf16(sa1.z, sa1.w); \
    w1.x = pk_bf16(sa2.x, sa2.y); w1.y = pk_bf16(sa2.z, sa2.w); \
    w1.z = pk_bf16(sa3.x, sa3.y); w1.w = pk_bf16(sa3.z, sa3.w); \
    *(uint4*)&LDS[(SLOT) * 4096 + wrE] = w0; \
    *(uint4*)&LDS[(SLOT) * 4096 + wrE + 128] = w1; \
} while (0)

#define LOADA do { \
    sa0 = *(const float4*)(aCur); sa1 = *(const float4*)(aCur + 4); \
    sa2 = *(const float4*)(aCur + 8); sa3 = *(const float4*)(aCur + 12); \
    aCur += 32; \
} while (0)

#define LOADB(Q) do { \
    Q##0 = *(const bf16x8*)(bCur); \
    Q##1 = *(const bf16x8*)(bCur + 16 * K_); \
    Q##2 = *(const bf16x8*)(bCur + 32 * K_); \
    Q##3 = *(const bf16x8*)(bCur + 48 * K_); \
    bCur += 32; \
} while (0)

#define MF(Av, Bv, C) __builtin_amdgcn_mfma_f32_16x16x32_bf16((Av), (Bv), (C), 0, 0, 0)

#define PHASE(BQC, BQN, DO_WR, DO_A, DO_B) do { \
    int swr = srd + 1; if (swr == 3) swr = 0; \
    if (DO_WR) STAGEWR(swr); \
    if (DO_A) LOADA; \
    if (DO_B) LOADB(BQN); \
    asm volatile("s_waitcnt lgkmcnt(0)" ::: "memory"); \
    __builtin_amdgcn_s_barrier(); \
    { \
        bf16x8 a0 = *(const bf16x8*)&LDS[srd * 4096 + rdE]; \
        bf16x8 a1 = *(const bf16x8*)&LDS[srd * 4096 + rdE + 512]; \
        bf16x8 a2 = *(const bf16x8*)&LDS[srd * 4096 + rdE + 1024]; \
        bf16x8 a3 = *(const bf16x8*)&LDS[srd * 4096 + rdE + 1536]; \
        __builtin_amdgcn_s_setprio(1); \
        acc[0][0] = MF(a0, BQC##0, acc[0][0]); \
        acc[0][1] = MF(a0, BQC##1, acc[0][1]); \
        acc[0][2] = MF(a0, BQC##2, acc[0][2]); \
        acc[0][3] = MF(a0, BQC##3, acc[0][3]); \
        acc[1][0] = MF(a1, BQC##0, acc[1][0]); \
        acc[1][1] = MF(a1, BQC##1, acc[1][1]); \
        acc[1][2] = MF(a1, BQC##2, acc[1][2]); \
        acc[1][3] = MF(a1, BQC##3, acc[1][3]); \
        acc[2][0] = MF(a2, BQC##0, acc[2][0]); \
        acc[2][1] = MF(a2, BQC##1, acc[2][1]); \
        acc[2][2] = MF(a2, BQC##2, acc[2][2]); \
        acc[2][3] = MF(a2, BQC##3, acc[2][3]); \
        acc[3][0] = MF(a3, BQC##0, acc[3][0]); \
        acc[3][1] = MF(a3, BQC##1, acc[3][1]); \
        acc[3][2] = MF(a3, BQC##2, acc[3][2]); \
        acc[3][3] = MF(a3, BQC##3, acc[3][3]); \
        __builtin_amdgcn_s_setprio(0); \
    } \
    srd = swr; \
} while (0)

    // Prologue: A(0) -> slot0; A(1) -> sa; B(0) -> bqA.
    LOADA;            // A(0)
    STAGEWR(0);       // compiler inserts vmcnt wait before cvt uses
    LOADA;            // A(1)
    LOADB(bqA);       // B(0)
    asm volatile("s_waitcnt lgkmcnt(0)" ::: "memory");
    __builtin_amdgcn_s_barrier();

#pragma unroll 1
    for (int i = 0; i < 31; ++i) {
        PHASE(bqA, bqB, 1, 1, 1);   // kh = 2i
        PHASE(bqB, bqA, 1, 1, 1);   // kh = 2i+1
    }
    PHASE(bqA, bqB, 1, 0, 1);       // kh = 62: write A(63), load B(63)
    PHASE(bqB, bqA, 0, 0, 0);       // kh = 63

    // ---------------- energy epilogue: pe = sum_h Weng[h]*tanh(dec[b,h]+C[m,h])
    const int b = mb >> 4;  // 16 m-blocks per batch (BM=128); no straddle
    float wv[4], dv[4];
#pragma unroll
    for (int ni = 0; ni < 4; ni++) {
        int h = nb * 128 + WC * 64 + ni * 16 + r;  // C/D col = lane&15
        wv[ni] = Weng[h];
        dv[ni] = decv[b * H_ + h];
    }
    float rs[4][4];
#pragma unroll
    for (int mi = 0; mi < 4; mi++)
#pragma unroll
        for (int rr = 0; rr < 4; rr++) rs[mi][rr] = 0.f;
#pragma unroll
    for (int mi = 0; mi < 4; mi++)
#pragma unroll
        for (int ni = 0; ni < 4; ni++)
#pragma unroll
            for (int rr = 0; rr < 4; rr++)
                rs[mi][rr] += wv[ni] * tanh_fast(dv[ni] + acc[mi][ni][rr]);
#pragma unroll
    for (int m2 = 1; m2 < 16; m2 <<= 1)
#pragma unroll
        for (int mi = 0; mi < 4; mi++)
#pragma unroll
            for (int rr = 0; rr < 4; rr++)
                rs[mi][rr] += __shfl_xor(rs[mi][rr], m2, 64);
    __syncthreads();
    float* esumF = (float*)&LDS[0];  // 2 WC-planes x 128 rows
    if (r == 0) {
#pragma unroll
        for (int mi = 0; mi < 4; mi++)
#pragma unroll
            for (int rr = 0; rr < 4; rr++)
                esumF[WC * 128 + WR * 64 + mi * 16 + g * 4 + rr] = rs[mi][rr];  // row=(lane>>4)*4+reg
    }
    __syncthreads();
    if (t < 128) {
        pe[(long)nb * M_ + (long)mb * 128 + t] = esumF[t] + esumF[128 + t];
    }
}

// ---------------------------------------------------------------- masked softmax over s (np partial planes)
__global__ __launch_bounds__(256) void softmax_k(const float* __restrict__ pe,
                                                 const int* __restrict__ slen,
                                                 float* __restrict__ alph, int np) {
    const int b = blockIdx.x, t = threadIdx.x;
    const int len = slen[b];
    __shared__ float sh[4];
    const float NEG = -__builtin_inff();
    float e[8];
    float mx = NEG;
#pragma unroll
    for (int i = 0; i < 8; i++) {
        int s = t + i * 256;
        float v = 0.f;
        for (int p = 0; p < np; p++) v += pe[(long)p * M_ + b * S_ + s];
        v = (s < len) ? v : NEG;
        e[i] = v;
        mx = fmaxf(mx, v);
    }
    for (int m2 = 1; m2 < 64; m2 <<= 1) mx = fmaxf(mx, __shfl_xor(mx, m2, 64));
    if ((t & 63) == 0) sh[t >> 6] = mx;
    __syncthreads();
    mx = fmaxf(fmaxf(sh[0], sh[1]), fmaxf(sh[2], sh[3]));
    float sum = 0.f;
#pragma unroll
    for (int i = 0; i < 8; i++) {
        float x = (e[i] == NEG) ? 0.f : __expf(e[i] - mx);
        e[i] = x;
        sum += x;
    }
    for (int m2 = 1; m2 < 64; m2 <<= 1) sum += __shfl_xor(sum, m2, 64);
    __syncthreads();
    if ((t & 63) == 0) sh[t >> 6] = sum;
    __syncthreads();
    sum = sh[0] + sh[1] + sh[2] + sh[3];
    float inv = 1.0f / sum;
#pragma unroll
    for (int i = 0; i < 8; i++) alph[b * S_ + t + i * 256] = e[i] * inv;
}

// ---------------------------------------------------------------- context (fp32 enc), fine-grained
__global__ __launch_bounds__(256) void context_f32(const float* __restrict__ enc,
                                                   const float* __restrict__ alph,
                                                   const int* __restrict__ slen,
                                                   float* __restrict__ out) {
    const int slot = blockIdx.x;
    const int b = slot & 31, ec = (slot >> 5) & 1, sc = slot >> 6;
    const int len = slen[b];
    const int s0 = sc * 64;
    if (s0 >= len) return;
    const int send = min(s0 + 64, len);
    __shared__ float al[64];
    const int t = threadIdx.x;
    if (t < 64) al[t] = alph[b * S_ + s0 + t];
    __syncthreads();
    const int e0 = ec * 1024 + t * 4;
    const float* base = enc + ((long)b * S_ + s0) * K_ + e0;
    float ax = 0.f, ay = 0.f, az = 0.f, aw = 0.f;
#pragma unroll 4
    for (int s = s0; s < send; ++s) {
        float a = al[s - s0];
        float4 v = *(const float4*)base;
        ax += a * v.x; ay += a * v.y; az += a * v.z; aw += a * v.w;
        base += K_;
    }
    float* o = out + (long)b * K_ + e0;
    atomicAdd(o + 0, ax);
    atomicAdd(o + 1, ay);
    atomicAdd(o + 2, az);
    atomicAdd(o + 3, aw);
}

extern "C" void kernel_launch(void* const* d_in, const int* in_sizes, int n_in,
                              void* d_out, int out_size, void* d_ws, size_t ws_size,
                              hipStream_t stream) {
    const float* dec_state = (const float*)d_in[0];  // [32,1,1024]
    const float* enc_state = (const float*)d_in[1];  // [32,2048,2048]
    const int*   src_len   = (const int*)d_in[2];    // [32]
    const float* W_enc     = (const float*)d_in[3];  // [1024,2048]
    const float* W_dec     = (const float*)d_in[4];  // [1024,1024]
    const float* W_energy  = (const float*)d_in[5];  // [1,1024]
    float* out = (float*)d_out;  // [0,65536): context [32,2048]; [65536,131072): alphas [32,2048]

    char* ws = (char*)d_ws;
    float* decv = (float*)ws;                                           // 128 KB @ 0
    float* pe   = (float*)(ws + (1 << 17));                             // 2 MB @ 128K (8 planes)
    unsigned short* Wenc_bf = (unsigned short*)(ws + 3 * (1 << 20));    // 4 MB @ 3M
    float* alph = out + 65536;

    hipMemsetAsync(out, 0, 65536 * sizeof(float), stream);

    cast8_k<<<1024, 256, 0, stream>>>(W_enc, Wenc_bf, (long)H_ * K_ / 8);
    dec_k<<<dim3(H_ / 4, B_), 256, 0, stream>>>(dec_state, W_dec, decv);

    gemm_fast<<<4096, 256, 0, stream>>>(enc_state, Wenc_bf, decv, W_energy, pe);
    softmax_k<<<B_, 256, 0, stream>>>(pe, src_len, alph, 8);
    context_f32<<<2048, 256, 0, stream>>>(enc_state, alph, src_len, out);
}